// Round 1
// baseline (805.418 us; speedup 1.0000x reference)
//
#include <hip/hip_runtime.h>
#include <cstddef>

#define B_ 4
#define C_ 512
#define L_ 2048
#define H_ 8
#define D_ 64

__device__ __forceinline__ float clip10(float v){ return fminf(fmaxf(v,-10.0f),10.0f); }

// ---------------------------------------------------------------------------
// Linear GEMM: out[b,o,l] = sum_c W[o,c]*inp[b,c,l] + bias[o] (+resid) (clip)
// BM=BN=128, BK=16, 256 threads, 8x8 per thread. fp32.
// ---------------------------------------------------------------------------
template<bool CLIP, bool RESID>
__global__ __launch_bounds__(256) void lin_gemm(
    const float* __restrict__ W, const float* __restrict__ inp,
    const float* __restrict__ bias, const float* __restrict__ resid,
    float* __restrict__ out, int OC)
{
  constexpr int BM=128, BN=128, BK=16, K=C_;
  __shared__ float sA[BK][BM+4];   // sA[k][m]
  __shared__ float sB[BK][BN+4];   // sB[k][n]
  const int t  = threadIdx.x;
  const int b  = blockIdx.z;
  const int m0 = blockIdx.y*BM, n0 = blockIdx.x*BN;
  const float* binp = inp + (size_t)b*K*L_;
  float acc[8][8];
#pragma unroll
  for (int i=0;i<8;i++)
#pragma unroll
    for (int j=0;j<8;j++) acc[i][j]=0.f;
  const int arow = t>>2,  akc = (t&3)<<2;   // A: 64 rows x 16 k per half
  const int bkr  = t>>4,  bnc = (t&15)<<3;  // B: 16 k-rows x 128 n
  const int tm8  = (t>>4)<<3, tn8 = (t&15)<<3;
  for (int k0=0;k0<K;k0+=BK){
    const float4 w0 = *(const float4*)(W + (size_t)(m0+arow)*K    + k0+akc);
    const float4 w1 = *(const float4*)(W + (size_t)(m0+arow+64)*K + k0+akc);
    const float4 g0 = *(const float4*)(binp + (size_t)(k0+bkr)*L_ + n0+bnc);
    const float4 g1 = *(const float4*)(binp + (size_t)(k0+bkr)*L_ + n0+bnc+4);
    __syncthreads();  // previous compute done before overwrite
    sA[akc+0][arow]=w0.x; sA[akc+1][arow]=w0.y; sA[akc+2][arow]=w0.z; sA[akc+3][arow]=w0.w;
    sA[akc+0][arow+64]=w1.x; sA[akc+1][arow+64]=w1.y; sA[akc+2][arow+64]=w1.z; sA[akc+3][arow+64]=w1.w;
    *(float4*)&sB[bkr][bnc]  =g0;
    *(float4*)&sB[bkr][bnc+4]=g1;
    __syncthreads();
#pragma unroll
    for (int k=0;k<BK;k++){
      const float4 a0=*(const float4*)&sA[k][tm8];
      const float4 a1=*(const float4*)&sA[k][tm8+4];
      const float4 c0=*(const float4*)&sB[k][tn8];
      const float4 c1=*(const float4*)&sB[k][tn8+4];
      const float am[8]={a0.x,a0.y,a0.z,a0.w,a1.x,a1.y,a1.z,a1.w};
      const float bn[8]={c0.x,c0.y,c0.z,c0.w,c1.x,c1.y,c1.z,c1.w};
#pragma unroll
      for (int i=0;i<8;i++)
#pragma unroll
        for (int j=0;j<8;j++) acc[i][j] += am[i]*bn[j];
    }
  }
#pragma unroll
  for (int i=0;i<8;i++){
    const int o = m0 + tm8 + i;
    const float bv = bias[o];
    const size_t off = ((size_t)b*OC + o)*L_ + n0 + tn8;
    float r[8];
#pragma unroll
    for (int j=0;j<8;j++) r[j]=acc[i][j]+bv;
    if (RESID){
      const float4 x0=*(const float4*)(resid+off);
      const float4 x1=*(const float4*)(resid+off+4);
      r[0]+=x0.x; r[1]+=x0.y; r[2]+=x0.z; r[3]+=x0.w;
      r[4]+=x1.x; r[5]+=x1.y; r[6]+=x1.z; r[7]+=x1.w;
    }
    if (CLIP){
#pragma unroll
      for (int j=0;j<8;j++) r[j]=clip10(r[j]);
    }
    const float4 s0={r[0],r[1],r[2],r[3]}, s1={r[4],r[5],r[6],r[7]};
    *(float4*)(out+off)  =s0;
    *(float4*)(out+off+4)=s1;
  }
}

// ---------------------------------------------------------------------------
// Attention: per (b,h,i-tile of 64). Streaming softmax (logits clipped to
// +-10 => no max subtraction needed). P reuses K's LDS buffer (<64KB static).
// ---------------------------------------------------------------------------
__global__ __launch_bounds__(256) void attention_k(
    const float* __restrict__ qkv, float* __restrict__ out)
{
  __shared__ float s_q [64][68];   // q[d][ii]
  __shared__ float s_kp[64][68];   // k[d][jj], then p[jj][ii]
  __shared__ float s_v [64][68];   // v[jj][d] (transposed)
  const int t  = threadIdx.x;
  const int i0 = blockIdx.x*64;
  const int h  = blockIdx.y;
  const int b  = blockIdx.z;
  const size_t qb = ((size_t)b*1536 + h*64)*L_;
  const size_t kb = qb + (size_t)512*L_;
  const size_t vb = qb + (size_t)1024*L_;
  {
    const int d=t>>2, col=(t&3)<<4;
    const float* src = qkv + qb + (size_t)d*L_ + i0 + col;
    const float4 v0=*(const float4*)src,     v1=*(const float4*)(src+4);
    const float4 v2=*(const float4*)(src+8), v3=*(const float4*)(src+12);
    *(float4*)&s_q[d][col]=v0;    *(float4*)&s_q[d][col+4]=v1;
    *(float4*)&s_q[d][col+8]=v2;  *(float4*)&s_q[d][col+12]=v3;
  }
  const int ti=t&15, tg=t>>4;      // phase1: ii=ti*4+r, jj=tg*4+c ; phase2: ii=ti*4+r, d=tg*4+di
  float o_acc[4][4];               // [di][r]
  float den[4];
#pragma unroll
  for(int i=0;i<4;i++){ den[i]=0.f;
#pragma unroll
    for(int j=0;j<4;j++) o_acc[i][j]=0.f; }

  for (int j0=0;j0<L_;j0+=64){
    {
      const int d=t>>2, col=(t&3)<<4;
      const float* ks = qkv + kb + (size_t)d*L_ + j0 + col;
      const float4 k0=*(const float4*)ks,     k1=*(const float4*)(ks+4);
      const float4 k2=*(const float4*)(ks+8), k3=*(const float4*)(ks+12);
      const float* vs = qkv + vb + (size_t)d*L_ + j0 + col;
      const float4 v0=*(const float4*)vs,     v1=*(const float4*)(vs+4);
      const float4 v2=*(const float4*)(vs+8), v3=*(const float4*)(vs+12);
      *(float4*)&s_kp[d][col]=k0;   *(float4*)&s_kp[d][col+4]=k1;
      *(float4*)&s_kp[d][col+8]=k2; *(float4*)&s_kp[d][col+12]=k3;
      s_v[col+ 0][d]=v0.x; s_v[col+ 1][d]=v0.y; s_v[col+ 2][d]=v0.z; s_v[col+ 3][d]=v0.w;
      s_v[col+ 4][d]=v1.x; s_v[col+ 5][d]=v1.y; s_v[col+ 6][d]=v1.z; s_v[col+ 7][d]=v1.w;
      s_v[col+ 8][d]=v2.x; s_v[col+ 9][d]=v2.y; s_v[col+10][d]=v2.z; s_v[col+11][d]=v2.w;
      s_v[col+12][d]=v3.x; s_v[col+13][d]=v3.y; s_v[col+14][d]=v3.z; s_v[col+15][d]=v3.w;
    }
    __syncthreads();
    // phase 1: S = Q^T K (4x4 per thread over d=64)
    float sv[4][4];
#pragma unroll
    for(int r=0;r<4;r++)
#pragma unroll
      for(int c=0;c<4;c++) sv[r][c]=0.f;
#pragma unroll 8
    for (int d=0;d<64;d++){
      const float4 qv=*(const float4*)&s_q [d][ti<<2];
      const float4 kv=*(const float4*)&s_kp[d][tg<<2];
      const float qa[4]={qv.x,qv.y,qv.z,qv.w}, ka[4]={kv.x,kv.y,kv.z,kv.w};
#pragma unroll
      for(int r=0;r<4;r++)
#pragma unroll
        for(int c=0;c<4;c++) sv[r][c]+=qa[r]*ka[c];
    }
    float pvv[4][4];
#pragma unroll
    for(int r=0;r<4;r++)
#pragma unroll
      for(int c=0;c<4;c++) pvv[r][c]=__expf(clip10(sv[r][c]*0.125f));
    __syncthreads();  // everyone done reading s_kp as K
#pragma unroll
    for(int r=0;r<4;r++)
#pragma unroll
      for(int c=0;c<4;c++) s_kp[(tg<<2)+c][(ti<<2)+r]=pvv[r][c];
    __syncthreads();
    // phase 2: O += V P^T, den += sum_j p
#pragma unroll 8
    for (int jj=0;jj<64;jj++){
      const float4 p =*(const float4*)&s_kp[jj][ti<<2];
      const float4 vv=*(const float4*)&s_v [jj][tg<<2];
      const float pa[4]={p.x,p.y,p.z,p.w}, va[4]={vv.x,vv.y,vv.z,vv.w};
#pragma unroll
      for(int di=0;di<4;di++)
#pragma unroll
        for(int r=0;r<4;r++) o_acc[di][r]+=va[di]*pa[r];
      den[0]+=p.x; den[1]+=p.y; den[2]+=p.z; den[3]+=p.w;
    }
    __syncthreads();  // before next staging overwrites
  }
  float inv[4];
#pragma unroll
  for(int r=0;r<4;r++) inv[r]=1.0f/den[r];
#pragma unroll
  for(int di=0;di<4;di++){
    const int d=(tg<<2)+di;
    const size_t off=((size_t)b*C_ + h*64 + d)*L_ + i0 + (ti<<2);
    const float4 rr={o_acc[di][0]*inv[0], o_acc[di][1]*inv[1],
                     o_acc[di][2]*inv[2], o_acc[di][3]*inv[3]};
    *(float4*)(out+off)=rr;
  }
}

// ---------------------------------------------------------------------------
// GroupNorm: one block per (b,g); group = 16 channels x 2048 = 32768 floats.
// ---------------------------------------------------------------------------
__global__ __launch_bounds__(256) void groupnorm_k(
    const float* __restrict__ y, const float* __restrict__ gamma,
    const float* __restrict__ beta, float* __restrict__ out)
{
  const int blk=blockIdx.x, b=blk>>5, g=blk&31;
  const size_t base=((size_t)b*C_ + g*16)*L_;
  const int t=threadIdx.x;
  float sum=0.f, sq=0.f;
#pragma unroll
  for (int i=0;i<32;i++){
    const float4 v=*(const float4*)(y+base+((size_t)(i*256+t)<<2));
    sum += v.x+v.y+v.z+v.w;
    sq  += v.x*v.x+v.y*v.y+v.z*v.z+v.w*v.w;
  }
  for (int off=32;off>0;off>>=1){
    sum += __shfl_down(sum,off);
    sq  += __shfl_down(sq,off);
  }
  __shared__ float red[8];
  __shared__ float s_mu, s_rs;
  if ((t&63)==0){ red[(t>>6)*2]=sum; red[(t>>6)*2+1]=sq; }
  __syncthreads();
  if (t==0){
    const float s=red[0]+red[2]+red[4]+red[6];
    const float q=red[1]+red[3]+red[5]+red[7];
    const float mu=s*(1.0f/32768.0f);
    const float var=q*(1.0f/32768.0f)-mu*mu;
    s_mu=mu; s_rs=rsqrtf(var+1e-5f);
  }
  __syncthreads();
  const float mu=s_mu, rs=s_rs;
#pragma unroll
  for (int i=0;i<32;i++){
    const int e=(i*256+t)<<2;
    const int c=(g<<4)+(e>>11);
    const float ga=gamma[c], be=beta[c];
    const float4 v=*(const float4*)(y+base+e);
    float4 r;
    r.x=(v.x-mu)*rs*ga+be;
    r.y=(v.y-mu)*rs*ga+be;
    r.z=(v.z-mu)*rs*ga+be;
    r.w=(v.w-mu)*rs*ga+be;
    *(float4*)(out+base+e)=r;
  }
}

// ---------------------------------------------------------------------------
extern "C" void kernel_launch(void* const* d_in, const int* in_sizes, int n_in,
                              void* d_out, int out_size, void* d_ws, size_t ws_size,
                              hipStream_t stream)
{
  (void)in_sizes; (void)n_in; (void)out_size; (void)ws_size;
  const float* x     = (const float*)d_in[0];
  const float* Wqkv  = (const float*)d_in[1];
  const float* bqkv  = (const float*)d_in[2];
  const float* Wproj = (const float*)d_in[3];
  const float* bproj = (const float*)d_in[4];
  const float* gamma = (const float*)d_in[5];
  const float* beta  = (const float*)d_in[6];
  float* out = (float*)d_out;
  float* ws  = (float*)d_ws;
  float* qkv  = ws;                         // 4*1536*2048 floats (48 MB)
  float* attn = ws + (size_t)4*1536*2048;   // 4*512*2048 floats (16 MB)
  float* y    = ws;                         // reuse qkv region (dead by then)

  lin_gemm<true ,false><<<dim3(16,12,4),256,0,stream>>>(Wqkv ,x   ,bqkv ,nullptr,qkv ,1536);
  attention_k          <<<dim3(32, 8,4),256,0,stream>>>(qkv, attn);
  lin_gemm<false,true ><<<dim3(16, 4,4),256,0,stream>>>(Wproj,attn,bproj,x      ,y   , 512);
  groupnorm_k          <<<dim3(128)    ,256,0,stream>>>(y, gamma, beta, out);
}

// Round 2
// 425.499 us; speedup vs baseline: 1.8929x; 1.8929x over previous
//
#include <hip/hip_runtime.h>
#include <cstddef>

#define B_ 4
#define C_ 512
#define L_ 2048
#define H_ 8
#define D_ 64

typedef __attribute__((ext_vector_type(8))) short  short8;   // 8 bf16 (4 VGPRs)
typedef __attribute__((ext_vector_type(4))) float  f32x4;
typedef __attribute__((ext_vector_type(4))) unsigned u32x4;

__device__ __forceinline__ float clip10(float v){ return fminf(fmaxf(v,-10.0f),10.0f); }

// round-to-nearest-even fp32 -> bf16 (finite inputs only; ours are clipped)
__device__ __forceinline__ unsigned short f2bf(float f){
  union { float f; unsigned u; } v; v.f = f;
  unsigned r = v.u + 0x7fffu + ((v.u >> 16) & 1u);
  return (unsigned short)(r >> 16);
}
__device__ __forceinline__ unsigned pk(float lo, float hi){
  return (unsigned)f2bf(lo) | ((unsigned)f2bf(hi) << 16);
}

// ---------------------------------------------------------------------------
// Linear GEMM: out[b,o,l] = sum_c W[o,c]*inp[...] + bias[o] (+resid) (clip)
// TRANSIN=false: inp is [b][c][l];  TRANSIN=true: inp is [b][l][c].
// BM=BN=128, BK=16, 256 threads, 8x8 per thread. fp32.
// ---------------------------------------------------------------------------
template<bool CLIP, bool RESID, bool TRANSIN>
__global__ __launch_bounds__(256) void lin_gemm(
    const float* __restrict__ W, const float* __restrict__ inp,
    const float* __restrict__ bias, const float* __restrict__ resid,
    float* __restrict__ out, int OC)
{
  constexpr int BM=128, BN=128, BK=16, K=C_;
  __shared__ float sA[BK][BM+4];   // sA[k][m]
  __shared__ float sB[BK][BN+4];   // sB[k][n]
  const int t  = threadIdx.x;
  const int b  = blockIdx.z;
  const int m0 = blockIdx.y*BM, n0 = blockIdx.x*BN;
  const float* binp = inp + (size_t)b*K*L_;   // same total elems either layout
  float acc[8][8];
#pragma unroll
  for (int i=0;i<8;i++)
#pragma unroll
    for (int j=0;j<8;j++) acc[i][j]=0.f;
  const int arow = t>>2,  akc = (t&3)<<2;   // A: 64 rows x 16 k per half
  const int bkr  = t>>4,  bnc = (t&15)<<3;  // B (natural): 16 k-rows x 128 n
  const int tln  = t>>2,  tc4 = (t&3)<<2;   // B (transposed input)
  const int tm8  = (t>>4)<<3, tn8 = (t&15)<<3;
  for (int k0=0;k0<K;k0+=BK){
    const float4 w0 = *(const float4*)(W + (size_t)(m0+arow)*K    + k0+akc);
    const float4 w1 = *(const float4*)(W + (size_t)(m0+arow+64)*K + k0+akc);
    float4 g0, g1;
    if (!TRANSIN){
      g0 = *(const float4*)(binp + (size_t)(k0+bkr)*L_ + n0+bnc);
      g1 = *(const float4*)(binp + (size_t)(k0+bkr)*L_ + n0+bnc+4);
    } else {
      g0 = *(const float4*)(binp + (size_t)(n0+tln)*K    + k0+tc4);
      g1 = *(const float4*)(binp + (size_t)(n0+tln+64)*K + k0+tc4);
    }
    __syncthreads();  // previous compute done before overwrite
    sA[akc+0][arow]=w0.x; sA[akc+1][arow]=w0.y; sA[akc+2][arow]=w0.z; sA[akc+3][arow]=w0.w;
    sA[akc+0][arow+64]=w1.x; sA[akc+1][arow+64]=w1.y; sA[akc+2][arow+64]=w1.z; sA[akc+3][arow+64]=w1.w;
    if (!TRANSIN){
      *(float4*)&sB[bkr][bnc]  =g0;
      *(float4*)&sB[bkr][bnc+4]=g1;
    } else {
      sB[tc4+0][tln]=g0.x; sB[tc4+1][tln]=g0.y; sB[tc4+2][tln]=g0.z; sB[tc4+3][tln]=g0.w;
      sB[tc4+0][tln+64]=g1.x; sB[tc4+1][tln+64]=g1.y; sB[tc4+2][tln+64]=g1.z; sB[tc4+3][tln+64]=g1.w;
    }
    __syncthreads();
#pragma unroll
    for (int k=0;k<BK;k++){
      const float4 a0=*(const float4*)&sA[k][tm8];
      const float4 a1=*(const float4*)&sA[k][tm8+4];
      const float4 c0=*(const float4*)&sB[k][tn8];
      const float4 c1=*(const float4*)&sB[k][tn8+4];
      const float am[8]={a0.x,a0.y,a0.z,a0.w,a1.x,a1.y,a1.z,a1.w};
      const float bn[8]={c0.x,c0.y,c0.z,c0.w,c1.x,c1.y,c1.z,c1.w};
#pragma unroll
      for (int i=0;i<8;i++)
#pragma unroll
        for (int j=0;j<8;j++) acc[i][j] += am[i]*bn[j];
    }
  }
#pragma unroll
  for (int i=0;i<8;i++){
    const int o = m0 + tm8 + i;
    const float bv = bias[o];
    const size_t off = ((size_t)b*OC + o)*L_ + n0 + tn8;
    float r[8];
#pragma unroll
    for (int j=0;j<8;j++) r[j]=acc[i][j]+bv;
    if (RESID){
      const float4 x0=*(const float4*)(resid+off);
      const float4 x1=*(const float4*)(resid+off+4);
      r[0]+=x0.x; r[1]+=x0.y; r[2]+=x0.z; r[3]+=x0.w;
      r[4]+=x1.x; r[5]+=x1.y; r[6]+=x1.z; r[7]+=x1.w;
    }
    if (CLIP){
#pragma unroll
      for (int j=0;j<8;j++) r[j]=clip10(r[j]);
    }
    const float4 s0={r[0],r[1],r[2],r[3]}, s1={r[4],r[5],r[6],r[7]};
    *(float4*)(out+off)  =s0;
    *(float4*)(out+off+4)=s1;
  }
}

// ---------------------------------------------------------------------------
// MFMA attention. Per block: 64 queries x (b,h); j-loop over 64-key tiles.
// S = Q^T K via mfma_f32_16x16x32_bf16 (A = Q[i][d], B = K[j][d], both
// transposed-on-stage). P round-trips LDS fp32 (C-layout -> A-layout).
// PV: A = P[i][j], B = V[d][j] (natural layout, no transpose).
// Output written transposed: outT[b][l][c] (coalesced along c).
// ---------------------------------------------------------------------------
#define QP 72   // bf16 row pitch for s_q/s_k/s_v (multiple of 8 -> 16B rows)
#define PP 68   // fp32 row pitch for s_p

__global__ __launch_bounds__(256) void attention_mfma(
    const float* __restrict__ qkv, float* __restrict__ outT)
{
  __shared__ unsigned short s_q[64*QP];   // [i][d] bf16
  __shared__ unsigned short s_k[64*QP];   // [j][d] bf16
  __shared__ unsigned short s_v[64*QP];   // [d][j] bf16
  __shared__ float          s_p[64*PP];   // [i][j] fp32
  const int t  = threadIdx.x;
  const int i0 = blockIdx.x*64;
  const int h  = blockIdx.y;
  const int b  = blockIdx.z;
  const size_t qb = ((size_t)b*1536 + h*64)*L_;
  const size_t kb = qb + (size_t)512*L_;
  const size_t vb = qb + (size_t)1024*L_;

  // ---- stage Q transposed: s_q[i][d], i local 0..63
  {
    const int dp = t & 31;          // d pair: d = 2dp, 2dp+1
    const int l0 = (t>>5)*8;        // 8 consecutive i per thread
    const float* r0 = qkv + qb + (size_t)(2*dp)*L_ + i0 + l0;
    const float* r1 = r0 + L_;
    const float4 a0=*(const float4*)r0,     a1=*(const float4*)(r0+4);
    const float4 b0=*(const float4*)r1,     b1=*(const float4*)(r1+4);
    unsigned* dq = (unsigned*)s_q;  // uint index = l*(QP/2) + dp
    dq[(l0+0)*(QP/2)+dp]=pk(a0.x,b0.x);
    dq[(l0+1)*(QP/2)+dp]=pk(a0.y,b0.y);
    dq[(l0+2)*(QP/2)+dp]=pk(a0.z,b0.z);
    dq[(l0+3)*(QP/2)+dp]=pk(a0.w,b0.w);
    dq[(l0+4)*(QP/2)+dp]=pk(a1.x,b1.x);
    dq[(l0+5)*(QP/2)+dp]=pk(a1.y,b1.y);
    dq[(l0+6)*(QP/2)+dp]=pk(a1.z,b1.z);
    dq[(l0+7)*(QP/2)+dp]=pk(a1.w,b1.w);
  }

  const int lane = t & 63;
  const int w    = t >> 6;        // wave id 0..3 -> i-strip w*16..w*16+15
  const int n    = lane & 15;
  const int q4   = lane >> 4;     // quad id 0..3

  f32x4 oacc[4];
  float dacc[4];
#pragma unroll
  for (int i=0;i<4;i++){ oacc[i]=(f32x4){0.f,0.f,0.f,0.f}; dacc[i]=0.f; }

  for (int j0=0;j0<L_;j0+=64){
    // ---- issue global loads for K (transpose) and V (natural)
    const int dp = t & 31, l0 = (t>>5)*8;
    const float* kr0 = qkv + kb + (size_t)(2*dp)*L_ + j0 + l0;
    const float* kr1 = kr0 + L_;
    const float4 ka0=*(const float4*)kr0,   ka1=*(const float4*)(kr0+4);
    const float4 kb0=*(const float4*)kr1,   kb1=*(const float4*)(kr1+4);
    const int vd = t>>2, vj = (t&3)*16;
    const float* vs = qkv + vb + (size_t)vd*L_ + j0 + vj;
    const float4 v0=*(const float4*)vs,     v1=*(const float4*)(vs+4);
    const float4 v2=*(const float4*)(vs+8), v3=*(const float4*)(vs+12);

    __syncthreads();   // all waves done reading previous s_k/s_v
    {
      unsigned* dk = (unsigned*)s_k;
      dk[(l0+0)*(QP/2)+dp]=pk(ka0.x,kb0.x);
      dk[(l0+1)*(QP/2)+dp]=pk(ka0.y,kb0.y);
      dk[(l0+2)*(QP/2)+dp]=pk(ka0.z,kb0.z);
      dk[(l0+3)*(QP/2)+dp]=pk(ka0.w,kb0.w);
      dk[(l0+4)*(QP/2)+dp]=pk(ka1.x,kb1.x);
      dk[(l0+5)*(QP/2)+dp]=pk(ka1.y,kb1.y);
      dk[(l0+6)*(QP/2)+dp]=pk(ka1.z,kb1.z);
      dk[(l0+7)*(QP/2)+dp]=pk(ka1.w,kb1.w);
      unsigned* dv = (unsigned*)&s_v[vd*QP + vj];
      const u32x4 w0 = {pk(v0.x,v0.y), pk(v0.z,v0.w), pk(v1.x,v1.y), pk(v1.z,v1.w)};
      const u32x4 w1 = {pk(v2.x,v2.y), pk(v2.z,v2.w), pk(v3.x,v3.y), pk(v3.z,v3.w)};
      *(u32x4*)dv     = w0;
      *(u32x4*)(dv+4) = w1;
    }
    __syncthreads();

    // ---- S = Q^T K : 4 mfma tiles (jt) x 2 k-steps (d0)
    f32x4 sacc[4];
#pragma unroll
    for (int jt=0;jt<4;jt++) sacc[jt]=(f32x4){0.f,0.f,0.f,0.f};
#pragma unroll
    for (int kk=0;kk<2;kk++){
      const int d0 = kk*32;
      const short8 aF = *(const short8*)&s_q[(w*16+n)*QP + d0 + 8*q4];
#pragma unroll
      for (int jt=0;jt<4;jt++){
        const short8 bF = *(const short8*)&s_k[(jt*16+n)*QP + d0 + 8*q4];
        sacc[jt] = __builtin_amdgcn_mfma_f32_16x16x32_bf16(aF, bF, sacc[jt], 0,0,0);
      }
    }

    // ---- softmax numerator: p = exp(clip(s*scale)); write to s_p (own rows)
#pragma unroll
    for (int jt=0;jt<4;jt++){
#pragma unroll
      for (int r=0;r<4;r++){
        const float e = __expf(clip10(sacc[jt][r]*0.125f));
        dacc[r] += e;
        s_p[(w*16 + q4*4 + r)*PP + jt*16 + n] = e;
      }
    }

    // ---- O += P V^T : A = P rows (wave-local), B = V
#pragma unroll
    for (int kk=0;kk<2;kk++){
      const int j0p = kk*32;
      const float* pr = &s_p[(w*16+n)*PP + j0p + 8*q4];
      const f32x4 p0 = *(const f32x4*)pr;
      const f32x4 p1 = *(const f32x4*)(pr+4);
      union { short8 v; unsigned u[4]; } ap;
      ap.u[0]=pk(p0[0],p0[1]); ap.u[1]=pk(p0[2],p0[3]);
      ap.u[2]=pk(p1[0],p1[1]); ap.u[3]=pk(p1[2],p1[3]);
#pragma unroll
      for (int dt=0;dt<4;dt++){
        const short8 bV = *(const short8*)&s_v[(dt*16+n)*QP + j0p + 8*q4];
        oacc[dt] = __builtin_amdgcn_mfma_f32_16x16x32_bf16(ap.v, bV, oacc[dt], 0,0,0);
      }
    }
  }

  // ---- denominator: reduce over the 16 lanes of each quad (cols of row i)
#pragma unroll
  for (int r=0;r<4;r++){
    float d = dacc[r];
    d += __shfl_xor(d, 1);
    d += __shfl_xor(d, 2);
    d += __shfl_xor(d, 4);
    d += __shfl_xor(d, 8);
    dacc[r] = 1.0f/d;
  }

  // ---- store O transposed: outT[b][l = i][c = h*64 + d], coalesced in d
#pragma unroll
  for (int dt=0;dt<4;dt++){
#pragma unroll
    for (int r=0;r<4;r++){
      const size_t off = ((size_t)b*L_ + i0 + w*16 + q4*4 + r)*C_ + h*64 + dt*16 + n;
      outT[off] = oacc[dt][r]*dacc[r];
    }
  }
}

// ---------------------------------------------------------------------------
// GroupNorm: one block per (b,g); group = 16 channels x 2048 = 32768 floats.
// ---------------------------------------------------------------------------
__global__ __launch_bounds__(256) void groupnorm_k(
    const float* __restrict__ y, const float* __restrict__ gamma,
    const float* __restrict__ beta, float* __restrict__ out)
{
  const int blk=blockIdx.x, b=blk>>5, g=blk&31;
  const size_t base=((size_t)b*C_ + g*16)*L_;
  const int t=threadIdx.x;
  float sum=0.f, sq=0.f;
#pragma unroll
  for (int i=0;i<32;i++){
    const float4 v=*(const float4*)(y+base+((size_t)(i*256+t)<<2));
    sum += v.x+v.y+v.z+v.w;
    sq  += v.x*v.x+v.y*v.y+v.z*v.z+v.w*v.w;
  }
  for (int off=32;off>0;off>>=1){
    sum += __shfl_down(sum,off);
    sq  += __shfl_down(sq,off);
  }
  __shared__ float red[8];
  __shared__ float s_mu, s_rs;
  if ((t&63)==0){ red[(t>>6)*2]=sum; red[(t>>6)*2+1]=sq; }
  __syncthreads();
  if (t==0){
    const float s=red[0]+red[2]+red[4]+red[6];
    const float q=red[1]+red[3]+red[5]+red[7];
    const float mu=s*(1.0f/32768.0f);
    const float var=q*(1.0f/32768.0f)-mu*mu;
    s_mu=mu; s_rs=rsqrtf(var+1e-5f);
  }
  __syncthreads();
  const float mu=s_mu, rs=s_rs;
#pragma unroll
  for (int i=0;i<32;i++){
    const int e=(i*256+t)<<2;
    const int c=(g<<4)+(e>>11);
    const float ga=gamma[c], be=beta[c];
    const float4 v=*(const float4*)(y+base+e);
    float4 r;
    r.x=(v.x-mu)*rs*ga+be;
    r.y=(v.y-mu)*rs*ga+be;
    r.z=(v.z-mu)*rs*ga+be;
    r.w=(v.w-mu)*rs*ga+be;
    *(float4*)(out+base+e)=r;
  }
}

// ---------------------------------------------------------------------------
extern "C" void kernel_launch(void* const* d_in, const int* in_sizes, int n_in,
                              void* d_out, int out_size, void* d_ws, size_t ws_size,
                              hipStream_t stream)
{
  (void)in_sizes; (void)n_in; (void)out_size; (void)ws_size;
  const float* x     = (const float*)d_in[0];
  const float* Wqkv  = (const float*)d_in[1];
  const float* bqkv  = (const float*)d_in[2];
  const float* Wproj = (const float*)d_in[3];
  const float* bproj = (const float*)d_in[4];
  const float* gamma = (const float*)d_in[5];
  const float* beta  = (const float*)d_in[6];
  float* out = (float*)d_out;
  float* ws  = (float*)d_ws;
  float* qkv   = ws;                         // 4*1536*2048 floats (48 MB)
  float* attnT = ws + (size_t)4*1536*2048;   // 4*2048*512 floats (16 MB), [b][l][c]
  float* y     = ws;                         // reuse qkv region (dead by then)

  lin_gemm<true ,false,false><<<dim3(16,12,4),256,0,stream>>>(Wqkv ,x    ,bqkv ,nullptr,qkv ,1536);
  attention_mfma             <<<dim3(32, 8,4),256,0,stream>>>(qkv, attnT);
  lin_gemm<false,true ,true ><<<dim3(16, 4,4),256,0,stream>>>(Wproj,attnT,bproj,x      ,y   , 512);
  groupnorm_k                <<<dim3(128)    ,256,0,stream>>>(y, gamma, beta, out);
}

// Round 3
// 220.979 us; speedup vs baseline: 3.6448x; 1.9255x over previous
//
#include <hip/hip_runtime.h>
#include <cstddef>

#define B_ 4
#define C_ 512
#define L_ 2048
#define H_ 8
#define D_ 64

typedef __attribute__((ext_vector_type(8))) short  short8;   // 8 bf16 (4 VGPRs)
typedef __attribute__((ext_vector_type(4))) float  f32x4;
typedef __attribute__((ext_vector_type(4))) unsigned short us4;

#define AS1 __attribute__((address_space(1)))
#define AS3 __attribute__((address_space(3)))

__device__ __forceinline__ float clip10(float v){ return fminf(fmaxf(v,-10.0f),10.0f); }

// round-to-nearest-even fp32 -> bf16 (finite inputs only; ours are clipped)
__device__ __forceinline__ unsigned short f2bf(float f){
  union { float f; unsigned u; } v; v.f = f;
  unsigned r = v.u + 0x7fffu + ((v.u >> 16) & 1u);
  return (unsigned short)(r >> 16);
}
__device__ __forceinline__ unsigned pk(float lo, float hi){
  return (unsigned)f2bf(lo) | ((unsigned)f2bf(hi) << 16);
}
// async 16B global -> LDS (direct-to-shared DMA)
__device__ __forceinline__ void gl16(const void* g, void* l){
  __builtin_amdgcn_global_load_lds((const AS1 unsigned*)g, (AS3 unsigned*)l, 16, 0, 0);
}

// ---------------------------------------------------------------------------
// Prep: fp32 -> bf16 weight conversion (Wqkv then Wproj, one grid)
// ---------------------------------------------------------------------------
__global__ __launch_bounds__(256) void prep_w(
    const float* __restrict__ Wq, const float* __restrict__ Wp,
    unsigned short* __restrict__ Wqb, unsigned short* __restrict__ Wpb)
{
  const int i = blockIdx.x*256 + threadIdx.x;   // float4 index
  const int NQ = 1536*512/4;
  const float* src; unsigned short* dst; int j;
  if (i < NQ){ src = Wq; dst = Wqb; j = i; }
  else       { src = Wp; dst = Wpb; j = i - NQ; }
  const float4 v = *(const float4*)(src + (size_t)j*4);
  const us4 o = { f2bf(v.x), f2bf(v.y), f2bf(v.z), f2bf(v.w) };
  *(us4*)(dst + (size_t)j*4) = o;
}

// ---------------------------------------------------------------------------
// Prep: x [b][c][l] fp32 -> xT [b][l][c] bf16 via 32x32 LDS tiles
// ---------------------------------------------------------------------------
__global__ __launch_bounds__(256) void prep_xT(
    const float* __restrict__ x, unsigned short* __restrict__ xT)
{
  __shared__ float tile[32][33];
  const int b = blockIdx.z, c0 = blockIdx.y*32, l0 = blockIdx.x*32;
  const int t = threadIdx.x;
  const int cr = t>>3, lc = (t&7)*4;
  const float4 v = *(const float4*)(x + ((size_t)b*C_ + c0+cr)*L_ + l0 + lc);
  tile[cr][lc]=v.x; tile[cr][lc+1]=v.y; tile[cr][lc+2]=v.z; tile[cr][lc+3]=v.w;
  __syncthreads();
  const int lr = t>>3, cc = (t&7)*4;
  const us4 o = { f2bf(tile[cc][lr]), f2bf(tile[cc+1][lr]),
                  f2bf(tile[cc+2][lr]), f2bf(tile[cc+3][lr]) };
  *(us4*)(xT + ((size_t)b*L_ + l0+lr)*C_ + c0 + cc) = o;
}

// ---------------------------------------------------------------------------
// bf16 MFMA GEMM, 128x128 tile, BK=64, K=512. A=W[m][k], B=Bin[b][n][k].
// LDS chunks XOR-swizzled: physical chunk = logical ^ (row&7).
// MODE 0 (QKV): +bias, clip, q/k stored transposed bf16 [b][l][512],
//               v stored natural bf16 [b][512][l].
// MODE 1 (proj): +bias, fp32 natural [b][512][l].
// ---------------------------------------------------------------------------
template<int MODE>
__global__ __launch_bounds__(256) void mfma_gemm(
    const unsigned short* __restrict__ Wb, const unsigned short* __restrict__ Bin,
    const float* __restrict__ bias,
    unsigned short* __restrict__ qT, unsigned short* __restrict__ kT,
    unsigned short* __restrict__ vN, float* __restrict__ yout)
{
  __shared__ unsigned short SA[128*64];   // [m][k'] bf16, 16KB
  __shared__ unsigned short SB[128*64];   // [n][k'] bf16, 16KB
  const int t = threadIdx.x;
  const int b = blockIdx.z;
  const int mb = blockIdx.y, n0 = blockIdx.x*128, m0 = mb*128;
  const int lane = t&63, w = t>>6, wm = w>>1, wn = w&1;
  const int n = lane&15, q4 = lane>>4;

  f32x4 acc[4][4];
#pragma unroll
  for (int i=0;i<4;i++)
#pragma unroll
    for (int j=0;j<4;j++) acc[i][j] = (f32x4){0.f,0.f,0.f,0.f};

  const unsigned short* Arow = Wb + (size_t)m0*512;
  const unsigned short* Brow = Bin + ((size_t)b*L_ + n0)*512;

  for (int kt=0; kt<8; kt++){
    const int k0 = kt*64;
    __syncthreads();                     // prev-iter fragment reads done
#pragma unroll
    for (int i=0;i<4;i++){
      const int ch = t + 256*i;          // 0..1023 : row=ch>>3, phys chunk=ch&7
      const int row = ch>>3, lc = (ch&7) ^ (row&7);
      gl16(Arow + (size_t)row*512 + k0 + lc*8, &SA[ch*8]);
      gl16(Brow + (size_t)row*512 + k0 + lc*8, &SB[ch*8]);
    }
    __syncthreads();                     // vmcnt(0) drained by compiler
#pragma unroll
    for (int kk=0;kk<2;kk++){
      short8 aF[4], bF[4];
      const int pc = ((kk*4+q4) ^ (n&7))*8;
#pragma unroll
      for (int mt=0;mt<4;mt++) aF[mt] = *(const short8*)&SA[(wm*64+mt*16+n)*64 + pc];
#pragma unroll
      for (int nt=0;nt<4;nt++) bF[nt] = *(const short8*)&SB[(wn*64+nt*16+n)*64 + pc];
#pragma unroll
      for (int mt=0;mt<4;mt++)
#pragma unroll
        for (int nt=0;nt<4;nt++)
          acc[mt][nt] = __builtin_amdgcn_mfma_f32_16x16x32_bf16(aF[mt], bF[nt], acc[mt][nt], 0,0,0);
    }
  }

  // ---- epilogue: C row = m (quad*4+reg), col = n (lane&15)
#pragma unroll
  for (int mt=0;mt<4;mt++){
    const int obase = m0 + wm*64 + mt*16 + q4*4;
    const float b0=bias[obase], b1=bias[obase+1], b2=bias[obase+2], b3=bias[obase+3];
#pragma unroll
    for (int nt=0;nt<4;nt++){
      const int l = n0 + wn*64 + nt*16 + n;
      float r0=acc[mt][nt][0]+b0, r1=acc[mt][nt][1]+b1,
            r2=acc[mt][nt][2]+b2, r3=acc[mt][nt][3]+b3;
      if (MODE==0){
        r0=clip10(r0); r1=clip10(r1); r2=clip10(r2); r3=clip10(r3);
        const int typ = mb>>2;                     // 0=q 1=k 2=v
        const int oin = obase - typ*512;
        if (typ < 2){
          unsigned short* dst = (typ==0) ? qT : kT;
          const us4 o = { f2bf(r0), f2bf(r1), f2bf(r2), f2bf(r3) };
          *(us4*)&dst[((size_t)b*L_ + l)*512 + oin] = o;   // [l][c], 8B store
        } else {
          unsigned short* dst = vN + ((size_t)b*512 + oin)*L_ + l;
          dst[0]=f2bf(r0); dst[(size_t)L_]=f2bf(r1);
          dst[(size_t)2*L_]=f2bf(r2); dst[(size_t)3*L_]=f2bf(r3);
        }
      } else {
        float* dst = yout + ((size_t)b*512 + obase)*L_ + l;
        dst[0]=r0; dst[(size_t)L_]=r1; dst[(size_t)2*L_]=r2; dst[(size_t)3*L_]=r3;
      }
    }
  }
}

// ---------------------------------------------------------------------------
// MFMA attention, all-DMA staging. qT/kT are [b][l][c] bf16 (c=h*64+d),
// vN is [b][512][l] bf16. Streaming softmax (clip => no max subtraction).
// Output attnT [b][l][c] bf16.
// ---------------------------------------------------------------------------
#define PP 68   // fp32 row pitch for s_p

__global__ __launch_bounds__(256) void attn_mfma(
    const unsigned short* __restrict__ qT, const unsigned short* __restrict__ kT,
    const unsigned short* __restrict__ vN, unsigned short* __restrict__ attnT)
{
  __shared__ unsigned short s_q[64*64];   // [i][d'] 8KB
  __shared__ unsigned short s_k[64*64];   // [j][d'] 8KB
  __shared__ unsigned short s_v[64*64];   // [d][j'] 8KB
  __shared__ float          s_p[64*PP];   // [i][j] fp32 17KB
  const int t  = threadIdx.x;
  const int i0 = blockIdx.x*64;
  const int h  = blockIdx.y;
  const int b  = blockIdx.z;
  const int lane = t&63, w = t>>6, n = lane&15, q4 = lane>>4;

  // ---- stage Q once (DMA): 512 chunks of 16B
  const unsigned short* qb = qT + ((size_t)b*L_ + i0)*512 + h*64;
#pragma unroll
  for (int i=0;i<2;i++){
    const int ch = t + 256*i;
    const int row = ch>>3, lc = (ch&7) ^ (row&7);
    gl16(qb + (size_t)row*512 + lc*8, &s_q[ch*8]);
  }
  const unsigned short* kb0 = kT + (size_t)b*L_*512 + h*64;
  const unsigned short* vb  = vN + ((size_t)b*512 + h*64)*L_;

  f32x4 oacc[4];
  float dacc[4];
#pragma unroll
  for (int i=0;i<4;i++){ oacc[i]=(f32x4){0.f,0.f,0.f,0.f}; dacc[i]=0.f; }

  for (int j0=0;j0<L_;j0+=64){
    __syncthreads();                       // prev-iter s_k/s_v reads done
#pragma unroll
    for (int i=0;i<2;i++){
      const int ch = t + 256*i;
      const int row = ch>>3, lc = (ch&7) ^ (row&7);
      gl16(kb0 + ((size_t)(j0+row))*512 + lc*8, &s_k[ch*8]);   // K rows j, k=d
      gl16(vb  + (size_t)row*L_ + j0 + lc*8,    &s_v[ch*8]);   // V rows d, k=j
    }
    __syncthreads();

    // ---- S = Q K^T : A=Q[i][d], B=K[j][d]
    f32x4 sacc[4];
#pragma unroll
    for (int jt=0;jt<4;jt++) sacc[jt]=(f32x4){0.f,0.f,0.f,0.f};
#pragma unroll
    for (int kk=0;kk<2;kk++){
      const int pc = ((kk*4+q4) ^ (n&7))*8;
      const short8 aF = *(const short8*)&s_q[(w*16+n)*64 + pc];
#pragma unroll
      for (int jt=0;jt<4;jt++){
        const short8 bF = *(const short8*)&s_k[(jt*16+n)*64 + pc];
        sacc[jt] = __builtin_amdgcn_mfma_f32_16x16x32_bf16(aF, bF, sacc[jt], 0,0,0);
      }
    }

    // ---- p = exp(clip(s/8)); accumulate denominator; stash to s_p
#pragma unroll
    for (int jt=0;jt<4;jt++)
#pragma unroll
      for (int r=0;r<4;r++){
        const float e = __expf(clip10(sacc[jt][r]*0.125f));
        dacc[r] += e;
        s_p[(w*16 + q4*4 + r)*PP + jt*16 + n] = e;
      }
    __syncthreads();

    // ---- O += P V^T : A=P[i][j] (repack C->A layout), B=V[d][j]
#pragma unroll
    for (int kk=0;kk<2;kk++){
      const float* pr = &s_p[(w*16+n)*PP + kk*32 + 8*q4];
      const f32x4 p0 = *(const f32x4*)pr;
      const f32x4 p1 = *(const f32x4*)(pr+4);
      union { short8 v; unsigned u[4]; } ap;
      ap.u[0]=pk(p0[0],p0[1]); ap.u[1]=pk(p0[2],p0[3]);
      ap.u[2]=pk(p1[0],p1[1]); ap.u[3]=pk(p1[2],p1[3]);
      const int pc = ((kk*4+q4) ^ (n&7))*8;
#pragma unroll
      for (int dt=0;dt<4;dt++){
        const short8 bV = *(const short8*)&s_v[(dt*16+n)*64 + pc];
        oacc[dt] = __builtin_amdgcn_mfma_f32_16x16x32_bf16(ap.v, bV, oacc[dt], 0,0,0);
      }
    }
  }

  // ---- denominator reduce over the 16 n-lanes of each quad
#pragma unroll
  for (int r=0;r<4;r++){
    float d = dacc[r];
    d += __shfl_xor(d, 1);
    d += __shfl_xor(d, 2);
    d += __shfl_xor(d, 4);
    d += __shfl_xor(d, 8);
    dacc[r] = 1.0f/d;
  }

  // ---- store bf16 [b][l][c]: row i = w*16+q4*4+r, col c = h*64+dt*16+n
#pragma unroll
  for (int dt=0;dt<4;dt++)
#pragma unroll
    for (int r=0;r<4;r++){
      const size_t off = ((size_t)b*L_ + i0 + w*16 + q4*4 + r)*512 + h*64 + dt*16 + n;
      attnT[off] = f2bf(oacc[dt][r]*dacc[r]);
    }
}

// ---------------------------------------------------------------------------
// GroupNorm over (y + x): one block per (b,g); 16 ch x 2048 = 32768 floats.
// ---------------------------------------------------------------------------
__global__ __launch_bounds__(256) void groupnorm_k(
    const float* __restrict__ y, const float* __restrict__ x,
    const float* __restrict__ gamma, const float* __restrict__ beta,
    float* __restrict__ out)
{
  const int blk=blockIdx.x, b=blk>>5, g=blk&31;
  const size_t base=((size_t)b*C_ + g*16)*L_;
  const int t=threadIdx.x;
  float sum=0.f, sq=0.f;
#pragma unroll
  for (int i=0;i<32;i++){
    const size_t e = base + ((size_t)(i*256+t)<<2);
    const float4 vy=*(const float4*)(y+e);
    const float4 vx=*(const float4*)(x+e);
    const float a=vy.x+vx.x, c=vy.y+vx.y, d=vy.z+vx.z, f=vy.w+vx.w;
    sum += a+c+d+f;
    sq  += a*a+c*c+d*d+f*f;
  }
  for (int off=32;off>0;off>>=1){
    sum += __shfl_down(sum,off);
    sq  += __shfl_down(sq,off);
  }
  __shared__ float red[8];
  __shared__ float s_mu, s_rs;
  if ((t&63)==0){ red[(t>>6)*2]=sum; red[(t>>6)*2+1]=sq; }
  __syncthreads();
  if (t==0){
    const float s=red[0]+red[2]+red[4]+red[6];
    const float q=red[1]+red[3]+red[5]+red[7];
    const float mu=s*(1.0f/32768.0f);
    const float var=q*(1.0f/32768.0f)-mu*mu;
    s_mu=mu; s_rs=rsqrtf(var+1e-5f);
  }
  __syncthreads();
  const float mu=s_mu, rs=s_rs;
#pragma unroll
  for (int i=0;i<32;i++){
    const int e=(i*256+t)<<2;
    const int c=(g<<4)+(e>>11);
    const float ga=gamma[c], be=beta[c];
    const float4 vy=*(const float4*)(y+base+e);
    const float4 vx=*(const float4*)(x+base+e);
    float4 r;
    r.x=((vy.x+vx.x)-mu)*rs*ga+be;
    r.y=((vy.y+vx.y)-mu)*rs*ga+be;
    r.z=((vy.z+vx.z)-mu)*rs*ga+be;
    r.w=((vy.w+vx.w)-mu)*rs*ga+be;
    *(float4*)(out+base+e)=r;
  }
}

// ---------------------------------------------------------------------------
extern "C" void kernel_launch(void* const* d_in, const int* in_sizes, int n_in,
                              void* d_out, int out_size, void* d_ws, size_t ws_size,
                              hipStream_t stream)
{
  (void)in_sizes; (void)n_in; (void)out_size; (void)ws_size;
  const float* x     = (const float*)d_in[0];
  const float* Wqkv  = (const float*)d_in[1];
  const float* bqkv  = (const float*)d_in[2];
  const float* Wproj = (const float*)d_in[3];
  const float* bproj = (const float*)d_in[4];
  const float* gamma = (const float*)d_in[5];
  const float* beta  = (const float*)d_in[6];
  float* out = (float*)d_out;
  char* ws = (char*)d_ws;

  const size_t MB = 1024*1024;
  unsigned short* qT    = (unsigned short*)(ws);            //  8 MB [b][l][512]
  unsigned short* kT    = (unsigned short*)(ws +  8*MB);    //  8 MB [b][l][512]
  unsigned short* vN    = (unsigned short*)(ws + 16*MB);    //  8 MB [b][512][l]
  unsigned short* attnT = (unsigned short*)(ws + 24*MB);    //  8 MB [b][l][512]
  unsigned short* xT    = (unsigned short*)(ws + 32*MB);    //  8 MB [b][l][512]
  unsigned short* Wqb   = (unsigned short*)(ws + 40*MB);    // 1.5 MB
  unsigned short* Wpb   = (unsigned short*)(ws + 42*MB);    // 0.5 MB
  float*          y     = (float*)        (ws + 43*MB);     // 16 MB [b][512][l]

  prep_w <<<dim3(1024),     256,0,stream>>>(Wqkv, Wproj, Wqb, Wpb);
  prep_xT<<<dim3(64,16,4),  256,0,stream>>>(x, xT);
  mfma_gemm<0><<<dim3(16,12,4),256,0,stream>>>(Wqb, xT,    bqkv , qT,kT,vN, nullptr);
  attn_mfma   <<<dim3(32, 8,4),256,0,stream>>>(qT, kT, vN, attnT);
  mfma_gemm<1><<<dim3(16, 4,4),256,0,stream>>>(Wpb, attnT, bproj, nullptr,nullptr,nullptr, y);
  groupnorm_k <<<dim3(128),    256,0,stream>>>(y, x, gamma, beta, out);
}

// Round 4
// 197.802 us; speedup vs baseline: 4.0718x; 1.1172x over previous
//
#include <hip/hip_runtime.h>
#include <cstddef>

#define B_ 4
#define C_ 512
#define L_ 2048
#define H_ 8
#define D_ 64

typedef __attribute__((ext_vector_type(8))) short  short8;   // 8 bf16 (4 VGPRs)
typedef __attribute__((ext_vector_type(4))) float  f32x4;
typedef __attribute__((ext_vector_type(4))) unsigned short us4;

#define AS1 __attribute__((address_space(1)))
#define AS3 __attribute__((address_space(3)))

__device__ __forceinline__ float clip10(float v){ return fminf(fmaxf(v,-10.0f),10.0f); }

// round-to-nearest-even fp32 -> bf16 (finite inputs only; ours are clipped)
__device__ __forceinline__ unsigned short f2bf(float f){
  union { float f; unsigned u; } v; v.f = f;
  unsigned r = v.u + 0x7fffu + ((v.u >> 16) & 1u);
  return (unsigned short)(r >> 16);
}
// async 16B global -> LDS (direct-to-shared DMA)
__device__ __forceinline__ void gl16(const void* g, void* l){
  __builtin_amdgcn_global_load_lds((const AS1 unsigned*)g, (AS3 unsigned*)l, 16, 0, 0);
}

// ---------------------------------------------------------------------------
// Prep: fp32 -> bf16 weight conversion (Wqkv then Wproj, one grid)
// ---------------------------------------------------------------------------
__global__ __launch_bounds__(256) void prep_w(
    const float* __restrict__ Wq, const float* __restrict__ Wp,
    unsigned short* __restrict__ Wqb, unsigned short* __restrict__ Wpb)
{
  const int i = blockIdx.x*256 + threadIdx.x;   // float4 index
  const int NQ = 1536*512/4;
  const float* src; unsigned short* dst; int j;
  if (i < NQ){ src = Wq; dst = Wqb; j = i; }
  else       { src = Wp; dst = Wpb; j = i - NQ; }
  const float4 v = *(const float4*)(src + (size_t)j*4);
  const us4 o = { f2bf(v.x), f2bf(v.y), f2bf(v.z), f2bf(v.w) };
  *(us4*)(dst + (size_t)j*4) = o;
}

// ---------------------------------------------------------------------------
// Prep: x [b][c][l] fp32 -> xT [b][l][c] bf16 via 32x32 LDS tiles
// ---------------------------------------------------------------------------
__global__ __launch_bounds__(256) void prep_xT(
    const float* __restrict__ x, unsigned short* __restrict__ xT)
{
  __shared__ float tile[32][33];
  const int b = blockIdx.z, c0 = blockIdx.y*32, l0 = blockIdx.x*32;
  const int t = threadIdx.x;
  const int cr = t>>3, lc = (t&7)*4;
  const float4 v = *(const float4*)(x + ((size_t)b*C_ + c0+cr)*L_ + l0 + lc);
  tile[cr][lc]=v.x; tile[cr][lc+1]=v.y; tile[cr][lc+2]=v.z; tile[cr][lc+3]=v.w;
  __syncthreads();
  const int lr = t>>3, cc = (t&7)*4;
  const us4 o = { f2bf(tile[cc][lr]), f2bf(tile[cc+1][lr]),
                  f2bf(tile[cc+2][lr]), f2bf(tile[cc+3][lr]) };
  *(us4*)(xT + ((size_t)b*L_ + l0+lr)*C_ + c0 + cc) = o;
}

// ---------------------------------------------------------------------------
// bf16 MFMA GEMM, 128x128 tile, BK=64, K=512. A=W[m][k], B=Bin[b][n][k].
// LDS chunks XOR-swizzled: physical chunk = logical ^ (row&7).
// MODE 0 (QKV): +bias, clip, q/k stored transposed bf16 [b][l][512],
//               v stored natural bf16 [b][512][l].
// MODE 1 (proj): +bias, fp32 natural [b][512][l].
// ---------------------------------------------------------------------------
template<int MODE>
__global__ __launch_bounds__(256) void mfma_gemm(
    const unsigned short* __restrict__ Wb, const unsigned short* __restrict__ Bin,
    const float* __restrict__ bias,
    unsigned short* __restrict__ qT, unsigned short* __restrict__ kT,
    unsigned short* __restrict__ vN, float* __restrict__ yout)
{
  __shared__ unsigned short SA[128*64];   // [m][k'] bf16, 16KB
  __shared__ unsigned short SB[128*64];   // [n][k'] bf16, 16KB
  const int t = threadIdx.x;
  const int b = blockIdx.z;
  const int mb = blockIdx.y, n0 = blockIdx.x*128, m0 = mb*128;
  const int lane = t&63, w = t>>6, wm = w>>1, wn = w&1;
  const int n = lane&15, q4 = lane>>4;

  f32x4 acc[4][4];
#pragma unroll
  for (int i=0;i<4;i++)
#pragma unroll
    for (int j=0;j<4;j++) acc[i][j] = (f32x4){0.f,0.f,0.f,0.f};

  const unsigned short* Arow = Wb + (size_t)m0*512;
  const unsigned short* Brow = Bin + ((size_t)b*L_ + n0)*512;

  for (int kt=0; kt<8; kt++){
    const int k0 = kt*64;
    __syncthreads();                     // prev-iter fragment reads done
#pragma unroll
    for (int i=0;i<4;i++){
      const int ch = t + 256*i;          // 0..1023 : row=ch>>3, phys chunk=ch&7
      const int row = ch>>3, lc = (ch&7) ^ (row&7);
      gl16(Arow + (size_t)row*512 + k0 + lc*8, &SA[ch*8]);
      gl16(Brow + (size_t)row*512 + k0 + lc*8, &SB[ch*8]);
    }
    __syncthreads();                     // vmcnt(0) drained by compiler
#pragma unroll
    for (int kk=0;kk<2;kk++){
      short8 aF[4], bF[4];
      const int pc = ((kk*4+q4) ^ (n&7))*8;
#pragma unroll
      for (int mt=0;mt<4;mt++) aF[mt] = *(const short8*)&SA[(wm*64+mt*16+n)*64 + pc];
#pragma unroll
      for (int nt=0;nt<4;nt++) bF[nt] = *(const short8*)&SB[(wn*64+nt*16+n)*64 + pc];
#pragma unroll
      for (int mt=0;mt<4;mt++)
#pragma unroll
        for (int nt=0;nt<4;nt++)
          acc[mt][nt] = __builtin_amdgcn_mfma_f32_16x16x32_bf16(aF[mt], bF[nt], acc[mt][nt], 0,0,0);
    }
  }

  // ---- epilogue: C row = m (quad*4+reg), col = n (lane&15)
#pragma unroll
  for (int mt=0;mt<4;mt++){
    const int obase = m0 + wm*64 + mt*16 + q4*4;
    const float b0=bias[obase], b1=bias[obase+1], b2=bias[obase+2], b3=bias[obase+3];
#pragma unroll
    for (int nt=0;nt<4;nt++){
      const int l = n0 + wn*64 + nt*16 + n;
      float r0=acc[mt][nt][0]+b0, r1=acc[mt][nt][1]+b1,
            r2=acc[mt][nt][2]+b2, r3=acc[mt][nt][3]+b3;
      if (MODE==0){
        r0=clip10(r0); r1=clip10(r1); r2=clip10(r2); r3=clip10(r3);
        const int typ = mb>>2;                     // 0=q 1=k 2=v
        const int oin = obase - typ*512;
        if (typ < 2){
          unsigned short* dst = (typ==0) ? qT : kT;
          const us4 o = { f2bf(r0), f2bf(r1), f2bf(r2), f2bf(r3) };
          *(us4*)&dst[((size_t)b*L_ + l)*512 + oin] = o;   // [l][c], 8B store
        } else {
          unsigned short* dst = vN + ((size_t)b*512 + oin)*L_ + l;
          dst[0]=f2bf(r0); dst[(size_t)L_]=f2bf(r1);
          dst[(size_t)2*L_]=f2bf(r2); dst[(size_t)3*L_]=f2bf(r3);
        }
      } else {
        float* dst = yout + ((size_t)b*512 + obase)*L_ + l;
        dst[0]=r0; dst[(size_t)L_]=r1; dst[(size_t)2*L_]=r2; dst[(size_t)3*L_]=r3;
      }
    }
  }
}

// ---------------------------------------------------------------------------
// MFMA attention v2: 128-query i-tile per block, 4 waves (wave = 32-i strip).
// Q fragments hoisted to registers; s_p (bf16) aliases s_q LDS.
// Softmax: p = exp2(med3(s*log2e/8, +-10*log2e)) -- streaming, no max-sub.
// ---------------------------------------------------------------------------
__global__ __launch_bounds__(256) void attn_mfma(
    const unsigned short* __restrict__ qT, const unsigned short* __restrict__ kT,
    const unsigned short* __restrict__ vN, unsigned short* __restrict__ attnT)
{
  __shared__ unsigned short s_pq[128*72];  // Q (pitch 64, 16KB) then P (pitch 72, 18KB)
  __shared__ unsigned short s_k[64*64];    // [j][d] 8KB
  __shared__ unsigned short s_v[64*64];    // [d][j] 8KB
  const int t  = threadIdx.x;
  const int i0 = blockIdx.x*128;
  const int h  = blockIdx.y;
  const int b  = blockIdx.z;
  const int lane = t&63, w = t>>6, n = lane&15, q4 = lane>>4;

  // ---- stage Q (DMA, XOR-swizzled chunks): 128 rows x 64 d bf16
  const unsigned short* qb = qT + ((size_t)b*L_ + i0)*512 + h*64;
#pragma unroll
  for (int i=0;i<4;i++){
    const int ch = t + 256*i, row = ch>>3, lc = (ch&7) ^ (row&7);
    gl16(qb + (size_t)row*512 + lc*8, &s_pq[ch*8]);
  }
  const unsigned short* kb0 = kT + (size_t)b*L_*512 + h*64;
  const unsigned short* vb  = vN + ((size_t)b*512 + h*64)*L_;
  __syncthreads();

  // ---- hoist Q A-fragments (loop-invariant): rows w*32+mt*16+n
  short8 qf[2][2];
#pragma unroll
  for (int mt=0;mt<2;mt++)
#pragma unroll
    for (int kk=0;kk<2;kk++)
      qf[mt][kk] = *(const short8*)&s_pq[(w*32+mt*16+n)*64 + ((kk*4+q4)^(n&7))*8];
  __syncthreads();   // all Q reads done before any wave writes P into s_pq

  f32x4 oacc[2][4];
  float dacc[2][4];
#pragma unroll
  for (int mt=0;mt<2;mt++)
#pragma unroll
    for (int i=0;i<4;i++){ oacc[mt][i]=(f32x4){0.f,0.f,0.f,0.f}; dacc[mt][i]=0.f; }

  const float SCL = 0.125f*1.44269504089f;   // log2(e)/8
  const float LIM = 14.4269504089f;          // 10*log2(e)
  const int   rsw = ((n>>2)&3)<<4;           // P-read column un-swizzle key

  for (int j0=0;j0<L_;j0+=64){
    __syncthreads();                         // prev-iter s_k/s_v reads done
#pragma unroll
    for (int i=0;i<2;i++){
      const int ch = t + 256*i, row = ch>>3, lc = (ch&7) ^ (row&7);
      gl16(kb0 + (size_t)(j0+row)*512 + lc*8, &s_k[ch*8]);   // K rows j, k=d
      gl16(vb  + (size_t)row*L_ + j0 + lc*8,  &s_v[ch*8]);   // V rows d, k=j
    }
    __syncthreads();

    // ---- S = Q K^T
    f32x4 sacc[2][4];
#pragma unroll
    for (int mt=0;mt<2;mt++)
#pragma unroll
      for (int jt=0;jt<4;jt++) sacc[mt][jt]=(f32x4){0.f,0.f,0.f,0.f};
#pragma unroll
    for (int kk=0;kk<2;kk++){
      short8 bK[4];
      const int pc = ((kk*4+q4) ^ (n&7))*8;
#pragma unroll
      for (int jt=0;jt<4;jt++) bK[jt] = *(const short8*)&s_k[(jt*16+n)*64 + pc];
#pragma unroll
      for (int mt=0;mt<2;mt++)
#pragma unroll
        for (int jt=0;jt<4;jt++)
          sacc[mt][jt] = __builtin_amdgcn_mfma_f32_16x16x32_bf16(qf[mt][kk], bK[jt], sacc[mt][jt], 0,0,0);
    }

    // ---- p = exp2(clamp(s*log2e/8)); accumulate den; write bf16 P (swizzled)
#pragma unroll
    for (int mt=0;mt<2;mt++)
#pragma unroll
      for (int jt=0;jt<4;jt++)
#pragma unroll
        for (int r=0;r<4;r++){
          const float e = __builtin_amdgcn_exp2f(
              __builtin_amdgcn_fmed3f(sacc[mt][jt][r]*SCL, -LIM, LIM));
          dacc[mt][r] += e;
          s_pq[(w*32+mt*16+q4*4+r)*72 + ((jt*16+n)^(q4<<4))] = f2bf(e);
        }
    // no barrier: each wave reads only the P rows it wrote

    // ---- O += P V^T
#pragma unroll
    for (int kk=0;kk<2;kk++){
      short8 pA[2], bV[4];
#pragma unroll
      for (int mt=0;mt<2;mt++)
        pA[mt] = *(const short8*)&s_pq[(w*32+mt*16+n)*72 + ((kk*32+q4*8)^rsw)];
      const int pc = ((kk*4+q4) ^ (n&7))*8;
#pragma unroll
      for (int dt=0;dt<4;dt++) bV[dt] = *(const short8*)&s_v[(dt*16+n)*64 + pc];
#pragma unroll
      for (int mt=0;mt<2;mt++)
#pragma unroll
        for (int dt=0;dt<4;dt++)
          oacc[mt][dt] = __builtin_amdgcn_mfma_f32_16x16x32_bf16(pA[mt], bV[dt], oacc[mt][dt], 0,0,0);
    }
  }

  // ---- denominator reduce over the 16 n-lanes of each quad
#pragma unroll
  for (int mt=0;mt<2;mt++)
#pragma unroll
    for (int r=0;r<4;r++){
      float d = dacc[mt][r];
      d += __shfl_xor(d, 1);
      d += __shfl_xor(d, 2);
      d += __shfl_xor(d, 4);
      d += __shfl_xor(d, 8);
      dacc[mt][r] = 1.0f/d;
    }

  // ---- store bf16 [b][l][c]
#pragma unroll
  for (int mt=0;mt<2;mt++)
#pragma unroll
    for (int dt=0;dt<4;dt++)
#pragma unroll
      for (int r=0;r<4;r++){
        const size_t off = ((size_t)b*L_ + i0 + w*32 + mt*16 + q4*4 + r)*512 + h*64 + dt*16 + n;
        attnT[off] = f2bf(oacc[mt][dt][r]*dacc[mt][r]);
      }
}

// ---------------------------------------------------------------------------
// GroupNorm over (y + x): one block per (b,g); 16 ch x 2048 = 32768 floats.
// ---------------------------------------------------------------------------
__global__ __launch_bounds__(256) void groupnorm_k(
    const float* __restrict__ y, const float* __restrict__ x,
    const float* __restrict__ gamma, const float* __restrict__ beta,
    float* __restrict__ out)
{
  const int blk=blockIdx.x, b=blk>>5, g=blk&31;
  const size_t base=((size_t)b*C_ + g*16)*L_;
  const int t=threadIdx.x;
  float sum=0.f, sq=0.f;
#pragma unroll
  for (int i=0;i<32;i++){
    const size_t e = base + ((size_t)(i*256+t)<<2);
    const float4 vy=*(const float4*)(y+e);
    const float4 vx=*(const float4*)(x+e);
    const float a=vy.x+vx.x, c=vy.y+vx.y, d=vy.z+vx.z, f=vy.w+vx.w;
    sum += a+c+d+f;
    sq  += a*a+c*c+d*d+f*f;
  }
  for (int off=32;off>0;off>>=1){
    sum += __shfl_down(sum,off);
    sq  += __shfl_down(sq,off);
  }
  __shared__ float red[8];
  __shared__ float s_mu, s_rs;
  if ((t&63)==0){ red[(t>>6)*2]=sum; red[(t>>6)*2+1]=sq; }
  __syncthreads();
  if (t==0){
    const float s=red[0]+red[2]+red[4]+red[6];
    const float q=red[1]+red[3]+red[5]+red[7];
    const float mu=s*(1.0f/32768.0f);
    const float var=q*(1.0f/32768.0f)-mu*mu;
    s_mu=mu; s_rs=rsqrtf(var+1e-5f);
  }
  __syncthreads();
  const float mu=s_mu, rs=s_rs;
#pragma unroll
  for (int i=0;i<32;i++){
    const int e=(i*256+t)<<2;
    const int c=(g<<4)+(e>>11);
    const float ga=gamma[c], be=beta[c];
    const float4 vy=*(const float4*)(y+base+e);
    const float4 vx=*(const float4*)(x+base+e);
    float4 r;
    r.x=((vy.x+vx.x)-mu)*rs*ga+be;
    r.y=((vy.y+vx.y)-mu)*rs*ga+be;
    r.z=((vy.z+vx.z)-mu)*rs*ga+be;
    r.w=((vy.w+vx.w)-mu)*rs*ga+be;
    *(float4*)(out+base+e)=r;
  }
}

// ---------------------------------------------------------------------------
extern "C" void kernel_launch(void* const* d_in, const int* in_sizes, int n_in,
                              void* d_out, int out_size, void* d_ws, size_t ws_size,
                              hipStream_t stream)
{
  (void)in_sizes; (void)n_in; (void)out_size; (void)ws_size;
  const float* x     = (const float*)d_in[0];
  const float* Wqkv  = (const float*)d_in[1];
  const float* bqkv  = (const float*)d_in[2];
  const float* Wproj = (const float*)d_in[3];
  const float* bproj = (const float*)d_in[4];
  const float* gamma = (const float*)d_in[5];
  const float* beta  = (const float*)d_in[6];
  float* out = (float*)d_out;
  char* ws = (char*)d_ws;

  const size_t MB = 1024*1024;
  unsigned short* qT    = (unsigned short*)(ws);            //  8 MB [b][l][512]
  unsigned short* kT    = (unsigned short*)(ws +  8*MB);    //  8 MB [b][l][512]
  unsigned short* vN    = (unsigned short*)(ws + 16*MB);    //  8 MB [b][512][l]
  unsigned short* attnT = (unsigned short*)(ws + 24*MB);    //  8 MB [b][l][512]
  unsigned short* xT    = (unsigned short*)(ws + 32*MB);    //  8 MB [b][l][512]
  unsigned short* Wqb   = (unsigned short*)(ws + 40*MB);    // 1.5 MB
  unsigned short* Wpb   = (unsigned short*)(ws + 42*MB);    // 0.5 MB
  float*          y     = (float*)        (ws + 43*MB);     // 16 MB [b][512][l]

  prep_w <<<dim3(1024),     256,0,stream>>>(Wqkv, Wproj, Wqb, Wpb);
  prep_xT<<<dim3(64,16,4),  256,0,stream>>>(x, xT);
  mfma_gemm<0><<<dim3(16,12,4),256,0,stream>>>(Wqb, xT,    bqkv , qT,kT,vN, nullptr);
  attn_mfma   <<<dim3(16, 8,4),256,0,stream>>>(qT, kT, vN, attnT);
  mfma_gemm<1><<<dim3(16, 4,4),256,0,stream>>>(Wpb, attnT, bproj, nullptr,nullptr,nullptr, y);
  groupnorm_k <<<dim3(128),    256,0,stream>>>(y, x, gamma, beta, out);
}